// Round 3
// baseline (277.845 us; speedup 1.0000x reference)
//
#include <hip/hip_runtime.h>
#include <hip/hip_bf16.h>
#include <math.h>
#include <float.h>

// b=8, c=64, H=W=64, KS=8 -> P = 57*57 = 3249.
// Stage 1 per (b,c): G[m,n] = <patch_m, patch_n> over P; corr = G/(sqrt(diag)sqrt(diag)P);
//   sort 64 m per column n desc; ranks {1,9,16,24,32,40,48,55,63} -> xp[b,c,576].
// Stage 2 per b: corr2[p,q] = sum_c Xn[c,p]Xn[c,q]/64 (Xn channel-normalized);
//   sort 576 p per column q desc; 115 ranks -> out.
//
// Shift set for stage 1 (covers all unique (m,n) + mirrors):
//   dj in 0..7; di in -7..7, with (dj==0 -> di>=0).  All windows anchored at kj=0.

#define IMGS 65
#define WSTR 67   // Wb row stride (odd -> <=2-way bank aliasing, free)
#define WIDX(s,kj) (((s)*8+(kj))*WSTR)

// ---------------- k1a: per-(b,c) Gram via separable windowed cross-correlation ----------
// grid = 512*8 (bc x di-pair), block = 256
__global__ __launch_bounds__(256) void k1a(const float* __restrict__ x,
                                           float* __restrict__ Gg) {
    __shared__ float img[64*IMGS + 16];
    __shared__ float Wb[16*8*WSTR];   // [s16][kj][a]

    const int t = threadIdx.x;
    const int bc = blockIdx.x >> 3;
    const int dp = blockIdx.x & 7;
    const float* src = x + (size_t)bc*4096;

    #pragma unroll
    for (int k = 0; k < 4; ++k) {
        int i4 = t + k*256;
        float4 v = ((const float4*)src)[i4];
        int fl = i4*4; int row = fl>>6, col = fl&63;
        float* d = &img[row*IMGS + col];
        d[0]=v.x; d[1]=v.y; d[2]=v.z; d[3]=v.w;
    }
    __syncthreads();

    // ---- phase A: row-window sums W[di,dj][a][kj], dj-quad per thread ----
    {
        const int half = t>>7, quad = (t>>6)&1, a = t&63;
        const int di = dp*2 - 7 + half;       // -7..8 (8 = invalid)
        const int djb = quad*4;
        const int alo = di<0 ? -di : 0, ahi = di>0 ? 63-di : 63;
        if (di <= 7 && a >= alo && a <= ahi) {
            const float* r0 = &img[a*IMGS];
            const float* r1 = &img[(a+di)*IMGS];
            const bool neg = di < 0;
            float w[4] = {0.f,0.f,0.f,0.f};
            float ra = r1[djb], rb = r1[djb+1], rc = r1[djb+2];
            for (int u = 0; u < 57; ++u) {
                float r0u = r0[u];
                float rd = r1[u+djb+3];
                w[0] = fmaf(r0u, ra, w[0]);
                w[1] = fmaf(r0u, rb, w[1]);
                w[2] = fmaf(r0u, rc, w[2]);
                w[3] = fmaf(r0u, rd, w[3]);
                ra = rb; rb = rc; rc = rd;
            }
            const int s16b = half*8 + djb;
            #pragma unroll
            for (int k=0;k<4;++k)
                if (!(neg && (djb+k)==0)) Wb[WIDX(s16b+k,0)+a] = w[k];
            for (int st = 1; st <= 7; ++st) {
                float r0m = r0[st-1], r0p = r0[st+56];
                #pragma unroll
                for (int k=0;k<4;++k) {
                    int dj = djb + k;
                    if (st <= 7-dj && !(neg && dj==0)) {
                        w[k] += r0p*r1[st+56+dj] - r0m*r1[st-1+dj];
                        Wb[WIDX(s16b+k,st)+a] = w[k];
                    }
                }
            }
        }
    }
    __syncthreads();

    // ---- phase B: column windows over a -> G entries (+ mirrors) ----
    if (t < 128) {
        const int s16 = t>>3, kj = t&7;
        const int half = s16>>3, dj = s16&7;
        const int di = dp*2 - 7 + half;
        if (di <= 7 && !(di<0 && dj==0) && kj <= 7-dj) {
            const int kilo = di<0 ? -di : 0;
            const int kihi = di>0 ? 7-di : 7;
            const float* wp = &Wb[WIDX(s16,kj)];
            float w = 0.f;
            #pragma unroll
            for (int A=0; A<57; ++A) w += wp[A + kilo];
            float* g = Gg + (size_t)bc*4096;
            for (int ki=kilo; ki<=kihi; ++ki) {
                if (ki > kilo) w += wp[ki+56] - wp[ki-1];
                int m = ki*8+kj, n = (ki+di)*8 + (kj+dj);
                g[m*64+n] = w;
                g[n*64+m] = w;
            }
        }
    }
}

// ---------------- k1b: normalize + cross-lane sort64 + ranked pool -> xp ----------------
// grid = 512*4, block = 256 (4 waves x 4 columns each), no LDS / no barriers
__global__ __launch_bounds__(256) void k1b(const float* __restrict__ Gg,
                                           float* __restrict__ xp) {
    const int t = threadIdx.x;
    const int bc = blockIdx.x >> 2, seg = blockIdx.x & 3;
    const int wv = t>>6, lane = t&63;
    const int n0 = seg*16 + wv*4;
    const float* g = Gg + (size_t)bc*4096;
    const int m = lane;
    float dvm = g[m*64+m];
    float invm = 1.0f / fmaxf(sqrtf(dvm), 1e-12f);
    const float sc = 1.0f/3249.0f;
    float v[4];
    #pragma unroll
    for (int c=0;c<4;++c) {
        float bn = __shfl(invm, n0+c, 64);
        v[c] = g[m*64 + n0+c] * invm * bn * sc;
    }
    // bitonic descending over lanes (element idx = lane), 4-column batch
    #pragma unroll
    for (int kk=2; kk<=64; kk<<=1) {
        #pragma unroll
        for (int j=kk>>1; j>0; j>>=1) {
            bool upper = (lane & j)!=0;
            bool dir0  = (lane & kk)==0;     // kk=64 -> always true -> global descending
            bool keep_max = dir0 ^ upper;
            float o[4];
            #pragma unroll
            for (int c=0;c<4;++c) o[c] = __shfl_xor(v[c], j, 64);
            #pragma unroll
            for (int c=0;c<4;++c) v[c] = keep_max ? fmaxf(v[c],o[c]) : fminf(v[c],o[c]);
        }
    }
    // ranks2 = {1,9,16,24,32,40,48,55,63}
    int ridx = -1;
    if      (lane== 1) ridx=0; else if (lane== 9) ridx=1; else if (lane==16) ridx=2;
    else if (lane==24) ridx=3; else if (lane==32) ridx=4; else if (lane==40) ridx=5;
    else if (lane==48) ridx=6; else if (lane==55) ridx=7; else if (lane==63) ridx=8;
    if (ridx >= 0) {
        #pragma unroll
        for (int c=0;c<4;++c)
            xp[(size_t)bc*576 + ridx*64 + n0+c] = v[c];
    }
}

// ---------------- k3a: corr2 columns (normalized, padded) -> c2 ----------------
// grid = 8*144 (4 q per block), block = 256
__global__ __launch_bounds__(256) void k3a(const float* __restrict__ xp,
                                           float* __restrict__ c2) {
    __shared__ float xq[4*64];
    __shared__ float iqv[4];
    const int t = threadIdx.x;
    const int b = blockIdx.x / 144, qg = blockIdx.x % 144;
    const int q0 = qg*4;
    const float* xpb = xp + (size_t)b*64*576;
    { int qq = t>>6, c = t&63; xq[qq*64+c] = xpb[c*576 + q0+qq]; }
    __syncthreads();
    if (t < 4) {
        float s = 0.f;
        #pragma unroll
        for (int c=0;c<64;++c) { float v = xq[t*64+c]; s = fmaf(v,v,s); }
        iqv[t] = 1.0f / fmaxf(sqrtf(s), 1e-12f);
    }
    __syncthreads();
    const float iq0 = iqv[0], iq1 = iqv[1], iq2 = iqv[2], iq3 = iqv[3];
    float* r0 = c2 + ((size_t)b*576 + q0)*1024;
    for (int p = t; p < 576; p += 256) {
        float s0=0,s1=0,s2=0,s3=0,sd=0;
        #pragma unroll
        for (int c=0;c<64;++c) {
            float xv = xpb[c*576+p];
            sd = fmaf(xv,xv,sd);
            s0 = fmaf(xv, xq[c],       s0);
            s1 = fmaf(xv, xq[64+c],    s1);
            s2 = fmaf(xv, xq[128+c],   s2);
            s3 = fmaf(xv, xq[192+c],   s3);
        }
        float ip = (1.0f/fmaxf(sqrtf(sd),1e-12f)) * 0.015625f;  // /64
        r0[p]        = s0*ip*iq0;
        r0[1024+p]   = s1*ip*iq1;
        r0[2048+p]   = s2*ip*iq2;
        r0[3072+p]   = s3*ip*iq3;
    }
    for (int p = 576+t; p < 1024; p += 256) {
        r0[p] = -FLT_MAX; r0[1024+p] = -FLT_MAX; r0[2048+p] = -FLT_MAX; r0[3072+p] = -FLT_MAX;
    }
}

// ---------------- k3b: per-wave register bitonic sort1024 + ranked scatter ----------------
// grid = 1152 (4 columns per block, one per wave), block = 256, no LDS / no barriers
__global__ __launch_bounds__(256) void k3b(const float* __restrict__ c2,
                                           float* __restrict__ out) {
    const int t = threadIdx.x;
    const int gw = blockIdx.x*4 + (t>>6);      // 0..4607 = b*576+q
    const int b = gw / 576, q = gw % 576;
    const int lane = t & 63;
    const float* row = c2 + (size_t)gw * 1024;
    float v[16];
    #pragma unroll
    for (int r=0;r<16;++r) v[r] = row[lane*16+r];

    #pragma unroll
    for (int kk=2; kk<=1024; kk<<=1) {
        #pragma unroll
        for (int j=kk>>1; j>0; j>>=1) {
            if (j >= 16) {
                const int jl = j>>4;
                bool upper = (lane & jl)!=0;
                bool dir0  = (lane & (kk>>4))==0;
                bool keep_max = dir0 ^ upper;
                float o[16];
                #pragma unroll
                for (int r=0;r<16;++r) o[r] = __shfl_xor(v[r], jl, 64);
                #pragma unroll
                for (int r=0;r<16;++r) v[r] = keep_max ? fmaxf(v[r],o[r]) : fminf(v[r],o[r]);
            } else {
                #pragma unroll
                for (int ra=0; ra<16; ++ra) {
                    if ((ra & j)==0) {
                        const int rb = ra | j;
                        bool dir0 = (kk>=16) ? ((lane & (kk>>4))==0) : ((ra & kk)==0);
                        float a = v[ra], bb = v[rb];
                        float mx = fmaxf(a,bb), mn = fminf(a,bb);
                        v[ra] = dir0 ? mx : mn;
                        v[rb] = dir0 ? mn : mx;
                    }
                }
            }
        }
    }

    // ranks = round(linspace(1,575,115)) == 1 + 5i + floor(2i/57) + (2i%57>=29)
    float* ob = out + (size_t)b*115*576 + q;
    #pragma unroll
    for (int r=0;r<16;++r) {
        int pos = lane*16 + r;
        int rr0 = (int)((float)pos * 0.1993f);
        #pragma unroll
        for (int dd=-1; dd<=2; ++dd) {
            int cand = rr0 + dd;
            if (cand >= 0 && cand < 115) {
                int ti = 2*cand;
                int rk = 1 + 5*cand + ti/57 + ((ti%57)>=29 ? 1:0);
                if (rk == pos) ob[(size_t)cand*576] = v[r];
            }
        }
    }
}

extern "C" void kernel_launch(void* const* d_in, const int* in_sizes, int n_in,
                              void* d_out, int out_size, void* d_ws, size_t ws_size,
                              hipStream_t stream) {
    const float* x = (const float*)d_in[0];   // [8,64,64,64] fp32
    float* out = (float*)d_out;               // [8,115,24,24] fp32
    float* xp = (float*)d_ws;                 // [8,64,576] = 294912 floats
    float* R  = xp + 294912;                  // union region (sequential lifetimes):
    float* Gg = R;                            //   [512,4096]      = 2,097,152 floats
    float* c2 = R;                            //   [8,576,1024]    = 4,718,592 floats
    // total ws use: (294912 + 4718592) * 4 B ~= 19.2 MiB

    k1a<<<dim3(4096), dim3(256), 0, stream>>>(x, Gg);
    k1b<<<dim3(2048), dim3(256), 0, stream>>>(Gg, xp);
    k3a<<<dim3(1152), dim3(256), 0, stream>>>(xp, c2);
    k3b<<<dim3(1152), dim3(256), 0, stream>>>(c2, out);
}

// Round 4
// 139.625 us; speedup vs baseline: 1.9899x; 1.9899x over previous
//
#include <hip/hip_runtime.h>
#include <hip/hip_bf16.h>
#include <math.h>
#include <float.h>

// b=8, c=64, H=W=64, KS=8 -> P = 57*57 = 3249.
// Stage 1 per (b,c): G[m,n] = <patch_m, patch_n> over P; corr = G/(sqrt(diag)sqrt(diag)P);
//   sort 64 m per column n desc; ranks {1,9,16,24,32,40,48,55,63} -> xp[b,c,576].
// Stage 2 per b: corr2[p,q] = sum_c Xn[c,p]Xn[c,q]/64 (Xn channel-normalized);
//   sort 576 p per column q desc; 115 ranks -> out.
//
// Shift set for stage 1: dj in 0..7; di in -7..7 with (dj==0 -> di>=0).
// Every unordered (m,n) pair covered exactly once; mirror-stored (G symmetric).

#define IMGS 65

// ---------------- k1a: per-(b,c) Gram via separable windowed cross-correlation ----------
// grid = 512*8 (bc x di-pair), block = 128 (2 waves: one di each)
__global__ __launch_bounds__(128) void k1a(const float* __restrict__ x,
                                           float* __restrict__ Gg) {
    __shared__ float img[64 * IMGS];        // 16.6 KB
    __shared__ float Wb[128 * 65];          // [(s16*8+st)][a], 33.3 KB

    const int t = threadIdx.x;
    const int bc = blockIdx.x >> 3;
    const int dp = blockIdx.x & 7;
    const float* src = x + (size_t)bc * 4096;

    #pragma unroll
    for (int k = 0; k < 8; ++k) {
        int i4 = t + k * 128;
        float4 v = ((const float4*)src)[i4];
        int fl = i4 * 4, row = fl >> 6, col = fl & 63;
        float* d = &img[row * IMGS + col];
        d[0] = v.x; d[1] = v.y; d[2] = v.z; d[3] = v.w;
    }
    __syncthreads();

    // ---- phase A: thread (di, a) computes ALL 8 dj window rows via shift register ----
    {
        const int half = t >> 6, a = t & 63;
        const int di = dp * 2 - 7 + half;          // -7..8 (8 invalid)
        const int alo = di < 0 ? -di : 0, ahi = di > 0 ? 63 - di : 63;
        if (di <= 7 && a >= alo && a <= ahi) {
            const float* r0 = &img[a * IMGS];
            const float* r1 = &img[(a + di) * IMGS];
            float w[8] = {0, 0, 0, 0, 0, 0, 0, 0};
            float s[8];
            #pragma unroll
            for (int k = 0; k < 7; ++k) s[k] = r1[k];
            #pragma unroll
            for (int u = 0; u < 57; ++u) {
                s[7] = r1[u + 7];
                float r0u = r0[u];
                #pragma unroll
                for (int k = 0; k < 8; ++k) w[k] = fmaf(r0u, s[k], w[k]);
                #pragma unroll
                for (int k = 0; k < 7; ++k) s[k] = s[k + 1];
            }
            // boundary captures -> slide phase does no further LDS reads
            float r0h[7], r0t[7], r1h[14], r1t[7];
            #pragma unroll
            for (int k = 0; k < 7; ++k) { r0h[k] = r0[k]; r0t[k] = r0[57 + k]; r1t[k] = r1[57 + k]; }
            #pragma unroll
            for (int k = 0; k < 14; ++k) r1h[k] = r1[k];
            const int sb = half * 8;
            #pragma unroll
            for (int dj = 0; dj < 8; ++dj) {
                if (di < 0 && dj == 0) continue;   // mirror of (di>0, dj=0)
                float ww = w[dj];
                Wb[((sb + dj) * 8 + 0) * 65 + a] = ww;
                #pragma unroll
                for (int st = 1; st < 8 - dj; ++st) {
                    ww += r0t[st - 1] * r1t[st + dj - 1] - r0h[st - 1] * r1h[st - 1 + dj];
                    Wb[((sb + dj) * 8 + st) * 65 + a] = ww;
                }
            }
        }
    }
    __syncthreads();

    // ---- phase B: thread (shift, st) -> column windows over a -> G entries (+ mirrors) ----
    {
        const int s16 = t >> 3, stc = t & 7;
        const int half = s16 >> 3, dj = s16 & 7;
        const int di = dp * 2 - 7 + half;
        if (di <= 7 && !(di < 0 && dj == 0) && stc < 8 - dj) {
            const int kilo = di < 0 ? -di : 0;
            const int kihi = di > 0 ? 7 - di : 7;
            const float* wp = &Wb[((half * 8 + dj) * 8 + stc) * 65];
            float w = 0.f;
            #pragma unroll
            for (int A = 0; A < 57; ++A) w += wp[A + kilo];
            float* g = Gg + (size_t)bc * 4096;
            for (int ki = kilo; ki <= kihi; ++ki) {
                if (ki > kilo) w += wp[ki + 56] - wp[ki - 1];
                int m = ki * 8 + stc, n = (ki + di) * 8 + (stc + dj);
                g[m * 64 + n] = w;
                g[n * 64 + m] = w;
            }
        }
    }
}

// ---------------- k1b: normalize + cross-lane sort64 + ranked pool -> xp ----------------
// grid = 512*4, block = 256 (4 waves x 4 columns each), no LDS / no barriers
__global__ __launch_bounds__(256) void k1b(const float* __restrict__ Gg,
                                           float* __restrict__ xp) {
    const int t = threadIdx.x;
    const int bc = blockIdx.x >> 2, seg = blockIdx.x & 3;
    const int wv = t >> 6, lane = t & 63;
    const int n0 = seg * 16 + wv * 4;
    const float* g = Gg + (size_t)bc * 4096;
    float invm = 1.0f / fmaxf(sqrtf(g[lane * 65]), 1e-12f);   // diag gather (L2)
    const float sc = 1.0f / 3249.0f;
    float v[4];
    #pragma unroll
    for (int c = 0; c < 4; ++c) {
        float bn = __shfl(invm, n0 + c, 64);
        v[c] = g[(n0 + c) * 64 + lane] * invm * bn * sc;   // symmetric: row read = coalesced
    }
    #pragma unroll
    for (int kk = 2; kk <= 64; kk <<= 1) {
        #pragma unroll
        for (int j = kk >> 1; j > 0; j >>= 1) {
            bool upper = (lane & j) != 0;
            bool dir0  = (lane & kk) == 0;
            bool keep_max = dir0 ^ upper;
            float o[4];
            #pragma unroll
            for (int c = 0; c < 4; ++c) o[c] = __shfl_xor(v[c], j, 64);
            #pragma unroll
            for (int c = 0; c < 4; ++c) v[c] = keep_max ? fmaxf(v[c], o[c]) : fminf(v[c], o[c]);
        }
    }
    int ridx = -1;
    if      (lane ==  1) ridx = 0; else if (lane ==  9) ridx = 1; else if (lane == 16) ridx = 2;
    else if (lane == 24) ridx = 3; else if (lane == 32) ridx = 4; else if (lane == 40) ridx = 5;
    else if (lane == 48) ridx = 6; else if (lane == 55) ridx = 7; else if (lane == 63) ridx = 8;
    if (ridx >= 0) {
        #pragma unroll
        for (int c = 0; c < 4; ++c)
            xp[(size_t)bc * 576 + ridx * 64 + n0 + c] = v[c];
    }
}

// ---------------- k3a: stage-2 Gram, LDS-tiled GEMM 64x64 tiles, fused norms ----------
// grid = 8*81 (b x 9x9 tiles), block = 256, 4x4 acc/thread
__global__ __launch_bounds__(256) void k3a(const float* __restrict__ xp,
                                           float* __restrict__ c2) {
    __shared__ __align__(16) float As[64 * 68];   // [c][pp], stride 68 keeps b128 alignment
    __shared__ __align__(16) float Bs[64 * 68];   // [c][qq]
    __shared__ __align__(16) float ipv[64], iqv[64];
    const int t = threadIdx.x;
    const int b = blockIdx.x / 81;
    const int r = blockIdx.x % 81;
    const int pt = r / 9, qt = r % 9;
    const int p0 = pt * 64, q0 = qt * 64;
    const float4* xp4 = (const float4*)(xp + (size_t)b * 64 * 576);

    #pragma unroll
    for (int k = 0; k < 4; ++k) {
        int c = k * 16 + (t >> 4), j = t & 15;
        float4 va = xp4[c * 144 + (p0 >> 2) + j];
        *(float4*)&As[c * 68 + j * 4] = va;
        float4 vb = xp4[c * 144 + (q0 >> 2) + j];
        *(float4*)&Bs[c * 68 + j * 4] = vb;
    }
    __syncthreads();

    if (t < 64) {
        float s = 0.f;
        #pragma unroll
        for (int c = 0; c < 64; ++c) { float vv = As[c * 68 + t]; s = fmaf(vv, vv, s); }
        ipv[t] = 1.0f / fmaxf(sqrtf(s), 1e-12f);
    } else if (t < 128) {
        int u = t - 64; float s = 0.f;
        #pragma unroll
        for (int c = 0; c < 64; ++c) { float vv = Bs[c * 68 + u]; s = fmaf(vv, vv, s); }
        iqv[u] = 1.0f / fmaxf(sqrtf(s), 1e-12f);
    }
    __syncthreads();

    const int tp = t & 15, tq = t >> 4;
    float acc[4][4] = {};
    #pragma unroll
    for (int c = 0; c < 64; ++c) {
        float4 a4 = *(const float4*)&As[c * 68 + tp * 4];
        float4 b4 = *(const float4*)&Bs[c * 68 + tq * 4];
        acc[0][0] = fmaf(a4.x, b4.x, acc[0][0]); acc[0][1] = fmaf(a4.x, b4.y, acc[0][1]);
        acc[0][2] = fmaf(a4.x, b4.z, acc[0][2]); acc[0][3] = fmaf(a4.x, b4.w, acc[0][3]);
        acc[1][0] = fmaf(a4.y, b4.x, acc[1][0]); acc[1][1] = fmaf(a4.y, b4.y, acc[1][1]);
        acc[1][2] = fmaf(a4.y, b4.z, acc[1][2]); acc[1][3] = fmaf(a4.y, b4.w, acc[1][3]);
        acc[2][0] = fmaf(a4.z, b4.x, acc[2][0]); acc[2][1] = fmaf(a4.z, b4.y, acc[2][1]);
        acc[2][2] = fmaf(a4.z, b4.z, acc[2][2]); acc[2][3] = fmaf(a4.z, b4.w, acc[2][3]);
        acc[3][0] = fmaf(a4.w, b4.x, acc[3][0]); acc[3][1] = fmaf(a4.w, b4.y, acc[3][1]);
        acc[3][2] = fmaf(a4.w, b4.z, acc[3][2]); acc[3][3] = fmaf(a4.w, b4.w, acc[3][3]);
    }

    float4 ip4 = *(const float4*)&ipv[tp * 4];
    #pragma unroll
    for (int qq = 0; qq < 4; ++qq) {
        int q = q0 + tq * 4 + qq;
        float iqs = iqv[tq * 4 + qq] * 0.015625f;   // /64
        float4 o;
        o.x = acc[0][qq] * ip4.x * iqs;
        o.y = acc[1][qq] * ip4.y * iqs;
        o.z = acc[2][qq] * ip4.z * iqs;
        o.w = acc[3][qq] * ip4.w * iqs;
        *(float4*)&c2[((size_t)(b * 576 + q)) * 1024 + p0 + tp * 4] = o;
    }

    if (pt == 8) {   // fill sort padding p=576..1023 for this block's q rows
        float4 pad = make_float4(-FLT_MAX, -FLT_MAX, -FLT_MAX, -FLT_MAX);
        for (int i = t; i < 64 * 112; i += 256) {
            int qq = i / 112, pj = i % 112;
            *(float4*)&c2[((size_t)(b * 576 + q0 + qq)) * 1024 + 576 + pj * 4] = pad;
        }
    }
}

// ---------------- k3b: per-wave register bitonic sort1024 + ranked scatter ----------------
// grid = 1152 (4 columns per block, one per wave), block = 256, no LDS / no barriers
__global__ __launch_bounds__(256) void k3b(const float* __restrict__ c2,
                                           float* __restrict__ out) {
    const int t = threadIdx.x;
    const int gw = blockIdx.x * 4 + (t >> 6);     // 0..4607 = b*576+q
    const int b = gw / 576, q = gw % 576;
    const int lane = t & 63;
    const float4* row4 = (const float4*)(c2 + (size_t)gw * 1024);
    float v[16];
    #pragma unroll
    for (int k = 0; k < 4; ++k) {
        float4 f = row4[lane * 4 + k];
        v[k * 4 + 0] = f.x; v[k * 4 + 1] = f.y; v[k * 4 + 2] = f.z; v[k * 4 + 3] = f.w;
    }

    #pragma unroll
    for (int kk = 2; kk <= 1024; kk <<= 1) {
        #pragma unroll
        for (int j = kk >> 1; j > 0; j >>= 1) {
            if (j >= 16) {
                const int jl = j >> 4;
                bool upper = (lane & jl) != 0;
                bool dir0  = (lane & (kk >> 4)) == 0;
                bool keep_max = dir0 ^ upper;
                float o[16];
                #pragma unroll
                for (int r = 0; r < 16; ++r) o[r] = __shfl_xor(v[r], jl, 64);
                #pragma unroll
                for (int r = 0; r < 16; ++r) v[r] = keep_max ? fmaxf(v[r], o[r]) : fminf(v[r], o[r]);
            } else {
                #pragma unroll
                for (int ra = 0; ra < 16; ++ra) {
                    if ((ra & j) == 0) {
                        const int rb = ra | j;
                        bool dir0 = (kk >= 16) ? ((lane & (kk >> 4)) == 0) : ((ra & kk) == 0);
                        float a = v[ra], bb = v[rb];
                        float mx = fmaxf(a, bb), mn = fminf(a, bb);
                        v[ra] = dir0 ? mx : mn;
                        v[rb] = dir0 ? mn : mx;
                    }
                }
            }
        }
    }

    // ranks = round(linspace(1,575,115)) == 1 + 5i + floor(2i/57) + (2i%57>=29)
    float* ob = out + (size_t)b * 115 * 576 + q;
    #pragma unroll
    for (int r = 0; r < 16; ++r) {
        int pos = lane * 16 + r;
        int rr0 = (int)((float)pos * 0.1993f);
        #pragma unroll
        for (int dd = -1; dd <= 2; ++dd) {
            int cand = rr0 + dd;
            if (cand >= 0 && cand < 115) {
                int ti = 2 * cand;
                int rk = 1 + 5 * cand + ti / 57 + ((ti % 57) >= 29 ? 1 : 0);
                if (rk == pos) ob[(size_t)cand * 576] = v[r];
            }
        }
    }
}

extern "C" void kernel_launch(void* const* d_in, const int* in_sizes, int n_in,
                              void* d_out, int out_size, void* d_ws, size_t ws_size,
                              hipStream_t stream) {
    const float* x = (const float*)d_in[0];   // [8,64,64,64] fp32
    float* out = (float*)d_out;               // [8,115,24,24] fp32
    float* xp = (float*)d_ws;                 // [8,64,576] = 294912 floats
    float* R  = xp + 294912;                  // union (sequential lifetimes):
    float* Gg = R;                            //   [512,4096]   = 2,097,152 floats
    float* c2 = R;                            //   [8,576,1024] = 4,718,592 floats
    // ws use: (294912 + 4718592)*4 B ~= 19.2 MiB

    k1a<<<dim3(4096), dim3(128), 0, stream>>>(x, Gg);
    k1b<<<dim3(2048), dim3(256), 0, stream>>>(Gg, xp);
    k3a<<<dim3(648),  dim3(256), 0, stream>>>(xp, c2);
    k3b<<<dim3(1152), dim3(256), 0, stream>>>(c2, out);
}